// Round 1
// baseline (439.268 us; speedup 1.0000x reference)
//
#include <hip/hip_runtime.h>
#include <stdint.h>
#include <stddef.h>

typedef __attribute__((ext_vector_type(8))) short bf16x8;
typedef __attribute__((ext_vector_type(4))) float f32x4;
typedef __attribute__((ext_vector_type(4))) unsigned int u32x4;

#define AS1 __attribute__((address_space(1)))
#define AS3 __attribute__((address_space(3)))

__device__ __forceinline__ void gll16(const void* g, void* l) {
  __builtin_amdgcn_global_load_lds((const AS1 unsigned int*)g, (AS3 unsigned int*)l, 16, 0, 0);
}

__device__ __forceinline__ uint16_t f2bf(float f) {
  uint32_t u = __builtin_bit_cast(uint32_t, f);
  u += 0x7fffu + ((u >> 16) & 1u);
  return (uint16_t)(u >> 16);
}
__device__ __forceinline__ float bf2f(uint16_t h) {
  uint32_t u = ((uint32_t)h) << 16;
  return __builtin_bit_cast(float, u);
}

// ---------------------------------------------------------------- f32 -> bf16
__global__ void cvt_f32_bf16(const float* __restrict__ in, uint16_t* __restrict__ out, int n8) {
  int i = blockIdx.x * blockDim.x + threadIdx.x;
  if (i >= n8) return;
  float4 a = reinterpret_cast<const float4*>(in)[2 * i];
  float4 b = reinterpret_cast<const float4*>(in)[2 * i + 1];
  union { uint16_t h[8]; u32x4 v; } u;
  u.h[0] = f2bf(a.x); u.h[1] = f2bf(a.y); u.h[2] = f2bf(a.z); u.h[3] = f2bf(a.w);
  u.h[4] = f2bf(b.x); u.h[5] = f2bf(b.y); u.h[6] = f2bf(b.z); u.h[7] = f2bf(b.w);
  reinterpret_cast<u32x4*>(out)[i] = u.v;
}

// ---------------------------------------------------------------- RoPE table
__global__ void rope_table(float* __restrict__ cosT, float* __restrict__ sinT) {
  int idx = blockIdx.x * blockDim.x + threadIdx.x;  // 2048*64
  int s = idx >> 6, i = idx & 63;
  // inv_freq = 10000^(-i/64) = exp(-i * ln(10000)/64)
  float invf = expf(-(float)i * (9.2103403719761836f / 64.0f));
  float f = (float)s * invf;
  cosT[idx] = cosf(f);
  sinT[idx] = sinf(f);
}

// ---------------------------------------------------------------- RoPE apply (in place on [2,16,2048,128] bf16)
__global__ void rope_apply(uint16_t* __restrict__ buf,
                           const float* __restrict__ cosT, const float* __restrict__ sinT) {
  int idx = blockIdx.x * blockDim.x + threadIdx.x;  // 2*16*2048*64 = 4194304
  int i = idx & 63;
  int s = (idx >> 6) & 2047;
  int bh = idx >> 17;
  size_t base = ((size_t)bh * 2048 + s) * 128;
  float x0 = bf2f(buf[base + i]);
  float x1 = bf2f(buf[base + i + 64]);
  float c = cosT[(s << 6) + i], sn = sinT[(s << 6) + i];
  buf[base + i]      = f2bf(x0 * c - x1 * sn);
  buf[base + i + 64] = f2bf(x1 * c + x0 * sn);
}

// ---------------------------------------------------------------- GEMM1: qkv = x @ Wqkv^T, scatter to Q/K/V [b,h,s,dh] bf16
__global__ __launch_bounds__(256) void gemm_qkv(
    const uint16_t* __restrict__ A,   // [4096][2048]
    const uint16_t* __restrict__ B,   // [6144][2048]
    uint16_t* __restrict__ Qb, uint16_t* __restrict__ Kb, uint16_t* __restrict__ Vb) {
  __shared__ uint16_t Ash[128 * 32];
  __shared__ uint16_t Bsh[128 * 32];
  const int t = threadIdx.x;
  const int lane = t & 63;
  const int w = t >> 6, wr = w >> 1, wc = w & 1;
  const int fr = lane & 15, fg = lane >> 4, fk = fg * 8;
  const int m0 = blockIdx.x * 128, n0 = blockIdx.y * 128;
  const int K = 2048;

  f32x4 acc[4][4];
#pragma unroll
  for (int i = 0; i < 4; i++)
#pragma unroll
    for (int j = 0; j < 4; j++) acc[i][j] = (f32x4)(0.0f);

  for (int kt = 0; kt < K; kt += 32) {
    __syncthreads();
    {
      int c0 = t, c1 = t + 256;
      gll16(&A[(size_t)(m0 + (c0 >> 2)) * K + kt + (c0 & 3) * 8], &Ash[(c0 & ~63) * 8]);
      gll16(&A[(size_t)(m0 + (c1 >> 2)) * K + kt + (c1 & 3) * 8], &Ash[(c1 & ~63) * 8]);
      gll16(&B[(size_t)(n0 + (c0 >> 2)) * K + kt + (c0 & 3) * 8], &Bsh[(c0 & ~63) * 8]);
      gll16(&B[(size_t)(n0 + (c1 >> 2)) * K + kt + (c1 & 3) * 8], &Bsh[(c1 & ~63) * 8]);
    }
    __syncthreads();
    bf16x8 af[4], bfr[4];
#pragma unroll
    for (int mi = 0; mi < 4; mi++) af[mi] = *(const bf16x8*)&Ash[(wr * 64 + mi * 16 + fr) * 32 + fk];
#pragma unroll
    for (int ni = 0; ni < 4; ni++) bfr[ni] = *(const bf16x8*)&Bsh[(wc * 64 + ni * 16 + fr) * 32 + fk];
#pragma unroll
    for (int mi = 0; mi < 4; mi++)
#pragma unroll
      for (int ni = 0; ni < 4; ni++)
        acc[mi][ni] = __builtin_amdgcn_mfma_f32_16x16x32_bf16(af[mi], bfr[ni], acc[mi][ni], 0, 0, 0);
  }

#pragma unroll
  for (int mi = 0; mi < 4; mi++) {
#pragma unroll
    for (int ni = 0; ni < 4; ni++) {
      int ng = n0 + wc * 64 + ni * 16 + fr;
      uint16_t* dst = (ng < 2048) ? Qb : (ng < 4096) ? Kb : Vb;
      int head = (ng >> 7) & 15, dd = ng & 127;
#pragma unroll
      for (int r = 0; r < 4; r++) {
        int mg = m0 + wr * 64 + mi * 16 + fg * 4 + r;
        int b = mg >> 11, si = mg & 2047;
        dst[((size_t)(b * 16 + head) * 2048 + si) * 128 + dd] = f2bf(acc[mi][ni][r]);
      }
    }
  }
}

// ---------------------------------------------------------------- GEMM2: out = z @ Wo^T (f32 out)
__global__ __launch_bounds__(256) void gemm_out_k(
    const uint16_t* __restrict__ A,   // [4096][2048] bf16 (z in [b,s,d])
    const uint16_t* __restrict__ B,   // [2048][2048] bf16 (Wo)
    float* __restrict__ C) {          // [4096][2048] f32
  __shared__ uint16_t Ash[128 * 32];
  __shared__ uint16_t Bsh[128 * 32];
  const int t = threadIdx.x;
  const int lane = t & 63;
  const int w = t >> 6, wr = w >> 1, wc = w & 1;
  const int fr = lane & 15, fg = lane >> 4, fk = fg * 8;
  const int m0 = blockIdx.x * 128, n0 = blockIdx.y * 128;
  const int K = 2048;

  f32x4 acc[4][4];
#pragma unroll
  for (int i = 0; i < 4; i++)
#pragma unroll
    for (int j = 0; j < 4; j++) acc[i][j] = (f32x4)(0.0f);

  for (int kt = 0; kt < K; kt += 32) {
    __syncthreads();
    {
      int c0 = t, c1 = t + 256;
      gll16(&A[(size_t)(m0 + (c0 >> 2)) * K + kt + (c0 & 3) * 8], &Ash[(c0 & ~63) * 8]);
      gll16(&A[(size_t)(m0 + (c1 >> 2)) * K + kt + (c1 & 3) * 8], &Ash[(c1 & ~63) * 8]);
      gll16(&B[(size_t)(n0 + (c0 >> 2)) * K + kt + (c0 & 3) * 8], &Bsh[(c0 & ~63) * 8]);
      gll16(&B[(size_t)(n0 + (c1 >> 2)) * K + kt + (c1 & 3) * 8], &Bsh[(c1 & ~63) * 8]);
    }
    __syncthreads();
    bf16x8 af[4], bfr[4];
#pragma unroll
    for (int mi = 0; mi < 4; mi++) af[mi] = *(const bf16x8*)&Ash[(wr * 64 + mi * 16 + fr) * 32 + fk];
#pragma unroll
    for (int ni = 0; ni < 4; ni++) bfr[ni] = *(const bf16x8*)&Bsh[(wc * 64 + ni * 16 + fr) * 32 + fk];
#pragma unroll
    for (int mi = 0; mi < 4; mi++)
#pragma unroll
      for (int ni = 0; ni < 4; ni++)
        acc[mi][ni] = __builtin_amdgcn_mfma_f32_16x16x32_bf16(af[mi], bfr[ni], acc[mi][ni], 0, 0, 0);
  }

#pragma unroll
  for (int mi = 0; mi < 4; mi++) {
#pragma unroll
    for (int ni = 0; ni < 4; ni++) {
      int ng = n0 + wc * 64 + ni * 16 + fr;
#pragma unroll
      for (int r = 0; r < 4; r++) {
        int mg = m0 + wr * 64 + mi * 16 + fg * 4 + r;
        C[(size_t)mg * 2048 + ng] = acc[mi][ni][r];
      }
    }
  }
}

// ---------------------------------------------------------------- flash attention (causal), Q/K/V [b,h,2048,128] bf16
// block: 256 thr (4 waves), 64 q-rows/block (16 per wave), kv tiles of 64
__global__ __launch_bounds__(256) void attn_kernel(
    const uint16_t* __restrict__ Qb, const uint16_t* __restrict__ Kb,
    const uint16_t* __restrict__ Vb, uint16_t* __restrict__ zb) {
  __shared__ uint16_t Ksh[64 * 128];   // swizzled: LDS chunk (row,cc) holds K[row][(cc^(row&7))*8..]
  __shared__ uint16_t Vsh[64 * 128];   // swizzled: chunk bits1-2 ^= (row>>3)&3
  __shared__ uint16_t Psh[4][16][72];  // per-wave P, +8 elem pad (row stride 144B, 16B aligned)

  const int t = threadIdx.x, lane = t & 63, w = t >> 6;
  const int fr = lane & 15, fg = lane >> 4, fk = fg * 8;
  const int qt = blockIdx.x, bh = blockIdx.y;
  const int q0 = qt * 64;
  const size_t hbase = (size_t)bh * 2048 * 128;
  const float scale = 0.08838834764831845f;

  // Q fragments in registers: rows q0 + w*16 + fr
  bf16x8 qf[4];
#pragma unroll
  for (int dc = 0; dc < 4; ++dc)
    qf[dc] = *(const bf16x8*)&Qb[hbase + (size_t)(q0 + w * 16 + fr) * 128 + dc * 32 + fk];

  f32x4 oacc[8];
#pragma unroll
  for (int i = 0; i < 8; i++) oacc[i] = (f32x4)(0.0f);
  float mrow[4], lrow[4];
#pragma unroll
  for (int r = 0; r < 4; r++) { mrow[r] = -INFINITY; lrow[r] = 0.0f; }

  const int ktiles = qt + 1;
  for (int kt = 0; kt < ktiles; ++kt) {
    __syncthreads();
    const uint16_t* Kg = Kb + hbase + (size_t)kt * 64 * 128;
    const uint16_t* Vg = Vb + hbase + (size_t)kt * 64 * 128;
#pragma unroll
    for (int i = 0; i < 4; i++) {
      int c = t + i * 256;              // 0..1023 chunks of 16B
      int row = c >> 4, cc = c & 15;
      int scc = cc ^ (row & 7);
      gll16(&Kg[row * 128 + scc * 8], &Ksh[(c & ~63) * 8]);
      int svc = cc ^ (((row >> 3) & 3) << 1);
      gll16(&Vg[row * 128 + svc * 8], &Vsh[(c & ~63) * 8]);
    }
    __syncthreads();

    // QK^T -> S[16q][64kv] per wave
    f32x4 sacc[4];
#pragma unroll
    for (int kv16 = 0; kv16 < 4; ++kv16) {
      sacc[kv16] = (f32x4)(0.0f);
#pragma unroll
      for (int dc = 0; dc < 4; ++dc) {
        int row = kv16 * 16 + fr;
        int sc = (dc * 4 + fg) ^ (row & 7);
        bf16x8 kf = *(const bf16x8*)&Ksh[row * 128 + sc * 8];
        sacc[kv16] = __builtin_amdgcn_mfma_f32_16x16x32_bf16(qf[dc], kf, sacc[kv16], 0, 0, 0);
      }
    }

    // scale + causal mask
    const int kv_base = kt * 64;
    float sv[4][4];
#pragma unroll
    for (int kv16 = 0; kv16 < 4; ++kv16)
#pragma unroll
      for (int r = 0; r < 4; ++r) {
        float v = sacc[kv16][r] * scale;
        int col = kv_base + kv16 * 16 + fr;
        int rowg = q0 + w * 16 + fg * 4 + r;
        sv[kv16][r] = (col > rowg) ? -INFINITY : v;
      }

    // online softmax
    float alpha[4], psum[4];
#pragma unroll
    for (int r = 0; r < 4; ++r) {
      float mx = fmaxf(fmaxf(sv[0][r], sv[1][r]), fmaxf(sv[2][r], sv[3][r]));
#pragma unroll
      for (int off = 1; off < 16; off <<= 1) mx = fmaxf(mx, __shfl_xor(mx, off, 64));
      float mnew = fmaxf(mrow[r], mx);
      alpha[r] = __expf(mrow[r] - mnew);   // exp(-inf)=0 on first tile
      mrow[r] = mnew;
      psum[r] = 0.0f;
    }
#pragma unroll
    for (int kv16 = 0; kv16 < 4; ++kv16)
#pragma unroll
      for (int r = 0; r < 4; ++r) {
        float p = __expf(sv[kv16][r] - mrow[r]);   // masked -> exp(-inf)=0
        psum[r] += p;
        Psh[w][fg * 4 + r][kv16 * 16 + fr] = f2bf(p);
      }
#pragma unroll
    for (int r = 0; r < 4; ++r) {
      float s = psum[r];
#pragma unroll
      for (int off = 1; off < 16; off <<= 1) s += __shfl_xor(s, off, 64);
      lrow[r] = lrow[r] * alpha[r] + s;
    }
#pragma unroll
    for (int i = 0; i < 8; i++)
#pragma unroll
      for (int r = 0; r < 4; r++) oacc[i][r] *= alpha[r];

    __syncthreads();  // P visible (also orders Psh write->read across LDS pipe)

    // PV: O += P[16][64] * V[64][128]
#pragma unroll
    for (int kc = 0; kc < 2; ++kc) {
      bf16x8 pf = *(const bf16x8*)&Psh[w][fr][kc * 32 + fk];
#pragma unroll
      for (int n8 = 0; n8 < 8; ++n8) {
        bf16x8 vf;
#pragma unroll
        for (int j = 0; j < 8; ++j) {
          int kr = kc * 32 + fk + j;
          int byt = kr * 256 + ((((n8 * 16 + fr) * 2)) ^ ((((kr >> 3) & 3)) << 5));
          vf[j] = *(const short*)((const char*)Vsh + byt);
        }
        oacc[n8] = __builtin_amdgcn_mfma_f32_16x16x32_bf16(pf, vf, oacc[n8], 0, 0, 0);
      }
    }
  }

  // normalize + write z in [b, s, h*128+d] layout
  const int b = bh >> 4, h = bh & 15;
#pragma unroll
  for (int n8 = 0; n8 < 8; ++n8)
#pragma unroll
    for (int r = 0; r < 4; ++r) {
      int rowg = q0 + w * 16 + fg * 4 + r;
      int d = n8 * 16 + fr;
      float o = oacc[n8][r] / lrow[r];
      zb[((size_t)b * 2048 + rowg) * 2048 + h * 128 + d] = f2bf(o);
    }
}

// ---------------------------------------------------------------- launch
extern "C" void kernel_launch(void* const* d_in, const int* in_sizes, int n_in,
                              void* d_out, int out_size, void* d_ws, size_t ws_size,
                              hipStream_t stream) {
  const float* x    = (const float*)d_in[0];
  const float* Wqkv = (const float*)d_in[1];
  const float* Wo   = (const float*)d_in[2];
  float* out = (float*)d_out;
  char* ws = (char*)d_ws;

  // workspace layout (bytes)
  uint16_t* Qb    = (uint16_t*)(ws + 0);            // 16,777,216
  uint16_t* Kb    = (uint16_t*)(ws + 16777216);     // 16,777,216
  uint16_t* Vb    = (uint16_t*)(ws + 33554432);     // 16,777,216
  uint16_t* xb    = (uint16_t*)(ws + 50331648);     // 16,777,216 (dead after gemm_qkv)
  uint16_t* zb    = (uint16_t*)(ws + 50331648);     // alias xb
  uint16_t* wqkvb = (uint16_t*)(ws + 67108864);     // 25,165,824
  uint16_t* wob   = (uint16_t*)(ws + 92274688);     //  8,388,608
  float*    cosT  = (float*)   (ws + 100663296);    //    524,288
  float*    sinT  = (float*)   (ws + 101187584);    //    524,288

  cvt_f32_bf16<<<4096, 256, 0, stream>>>(x, xb, 8388608 / 8);
  cvt_f32_bf16<<<6144, 256, 0, stream>>>(Wqkv, wqkvb, 12582912 / 8);
  cvt_f32_bf16<<<2048, 256, 0, stream>>>(Wo, wob, 4194304 / 8);
  rope_table<<<512, 256, 0, stream>>>(cosT, sinT);

  gemm_qkv<<<dim3(32, 48), 256, 0, stream>>>(xb, wqkvb, Qb, Kb, Vb);

  rope_apply<<<16384, 256, 0, stream>>>(Qb, cosT, sinT);
  rope_apply<<<16384, 256, 0, stream>>>(Kb, cosT, sinT);

  attn_kernel<<<dim3(32, 32), 256, 0, stream>>>(Qb, Kb, Vb, zb);

  gemm_out_k<<<dim3(32, 16), 256, 0, stream>>>(zb, wob, out);
}

// Round 2
// 416.752 us; speedup vs baseline: 1.0540x; 1.0540x over previous
//
#include <hip/hip_runtime.h>
#include <stdint.h>
#include <stddef.h>

typedef __attribute__((ext_vector_type(8))) short bf16x8;
typedef __attribute__((ext_vector_type(4))) float f32x4;
typedef __attribute__((ext_vector_type(4))) unsigned int u32x4;

#define AS1 __attribute__((address_space(1)))
#define AS3 __attribute__((address_space(3)))

__device__ __forceinline__ void gll16(const void* g, void* l) {
  __builtin_amdgcn_global_load_lds((const AS1 unsigned int*)g, (AS3 unsigned int*)l, 16, 0, 0);
}

__device__ __forceinline__ uint16_t f2bf(float f) {
  uint32_t u = __builtin_bit_cast(uint32_t, f);
  u += 0x7fffu + ((u >> 16) & 1u);
  return (uint16_t)(u >> 16);
}
__device__ __forceinline__ float bf2f(uint16_t h) {
  uint32_t u = ((uint32_t)h) << 16;
  return __builtin_bit_cast(float, u);
}

// ---------------------------------------------------------------- f32 -> bf16
__global__ void cvt_f32_bf16(const float* __restrict__ in, uint16_t* __restrict__ out, int n8) {
  int i = blockIdx.x * blockDim.x + threadIdx.x;
  if (i >= n8) return;
  float4 a = reinterpret_cast<const float4*>(in)[2 * i];
  float4 b = reinterpret_cast<const float4*>(in)[2 * i + 1];
  union { uint16_t h[8]; u32x4 v; } u;
  u.h[0] = f2bf(a.x); u.h[1] = f2bf(a.y); u.h[2] = f2bf(a.z); u.h[3] = f2bf(a.w);
  u.h[4] = f2bf(b.x); u.h[5] = f2bf(b.y); u.h[6] = f2bf(b.z); u.h[7] = f2bf(b.w);
  reinterpret_cast<u32x4*>(out)[i] = u.v;
}

// ---------------------------------------------------------------- RoPE table
__global__ void rope_table(float* __restrict__ cosT, float* __restrict__ sinT) {
  int idx = blockIdx.x * blockDim.x + threadIdx.x;  // 2048*64
  int s = idx >> 6, i = idx & 63;
  float invf = expf(-(float)i * (9.2103403719761836f / 64.0f));
  float f = (float)s * invf;
  cosT[idx] = cosf(f);
  sinT[idx] = sinf(f);
}

// ---------------------------------------------------------------- RoPE apply (in place on [2,16,2048,128] bf16)
__global__ void rope_apply(uint16_t* __restrict__ buf,
                           const float* __restrict__ cosT, const float* __restrict__ sinT) {
  int idx = blockIdx.x * blockDim.x + threadIdx.x;  // 2*16*2048*64 = 4194304
  int i = idx & 63;
  int s = (idx >> 6) & 2047;
  int bh = idx >> 17;
  size_t base = ((size_t)bh * 2048 + s) * 128;
  float x0 = bf2f(buf[base + i]);
  float x1 = bf2f(buf[base + i + 64]);
  float c = cosT[(s << 6) + i], sn = sinT[(s << 6) + i];
  buf[base + i]      = f2bf(x0 * c - x1 * sn);
  buf[base + i + 64] = f2bf(x1 * c + x0 * sn);
}

// ---------------------------------------------------------------- GEMM1: qkv = x @ Wqkv^T
// Q,K scatter to [b,h,s,dh]; V scatters TRANSPOSED to Vt[b,h,dh,s]
__global__ __launch_bounds__(256) void gemm_qkv(
    const uint16_t* __restrict__ A,   // [4096][2048]
    const uint16_t* __restrict__ B,   // [6144][2048]
    uint16_t* __restrict__ Qb, uint16_t* __restrict__ Kb, uint16_t* __restrict__ Vt) {
  __shared__ uint16_t Ash[128 * 32];
  __shared__ uint16_t Bsh[128 * 32];
  const int t = threadIdx.x;
  const int lane = t & 63;
  const int w = t >> 6, wr = w >> 1, wc = w & 1;
  const int fr = lane & 15, fg = lane >> 4, fk = fg * 8;
  const int m0 = blockIdx.x * 128, n0 = blockIdx.y * 128;
  const int K = 2048;

  f32x4 acc[4][4];
#pragma unroll
  for (int i = 0; i < 4; i++)
#pragma unroll
    for (int j = 0; j < 4; j++) acc[i][j] = (f32x4)(0.0f);

  for (int kt = 0; kt < K; kt += 32) {
    __syncthreads();
    {
      int c0 = t, c1 = t + 256;
      gll16(&A[(size_t)(m0 + (c0 >> 2)) * K + kt + (c0 & 3) * 8], &Ash[(c0 & ~63) * 8]);
      gll16(&A[(size_t)(m0 + (c1 >> 2)) * K + kt + (c1 & 3) * 8], &Ash[(c1 & ~63) * 8]);
      gll16(&B[(size_t)(n0 + (c0 >> 2)) * K + kt + (c0 & 3) * 8], &Bsh[(c0 & ~63) * 8]);
      gll16(&B[(size_t)(n0 + (c1 >> 2)) * K + kt + (c1 & 3) * 8], &Bsh[(c1 & ~63) * 8]);
    }
    __syncthreads();
    bf16x8 af[4], bfr[4];
#pragma unroll
    for (int mi = 0; mi < 4; mi++) af[mi] = *(const bf16x8*)&Ash[(wr * 64 + mi * 16 + fr) * 32 + fk];
#pragma unroll
    for (int ni = 0; ni < 4; ni++) bfr[ni] = *(const bf16x8*)&Bsh[(wc * 64 + ni * 16 + fr) * 32 + fk];
#pragma unroll
    for (int mi = 0; mi < 4; mi++)
#pragma unroll
      for (int ni = 0; ni < 4; ni++)
        acc[mi][ni] = __builtin_amdgcn_mfma_f32_16x16x32_bf16(af[mi], bfr[ni], acc[mi][ni], 0, 0, 0);
  }

#pragma unroll
  for (int mi = 0; mi < 4; mi++) {
#pragma unroll
    for (int ni = 0; ni < 4; ni++) {
      int ng = n0 + wc * 64 + ni * 16 + fr;
      int head = (ng >> 7) & 15, dd = ng & 127;
#pragma unroll
      for (int r = 0; r < 4; r++) {
        int mg = m0 + wr * 64 + mi * 16 + fg * 4 + r;
        int b = mg >> 11, si = mg & 2047;
        uint16_t val = f2bf(acc[mi][ni][r]);
        if (ng < 4096) {
          uint16_t* dst = (ng < 2048) ? Qb : Kb;
          dst[((size_t)(b * 16 + head) * 2048 + si) * 128 + dd] = val;
        } else {
          Vt[((size_t)(b * 16 + head) * 128 + dd) * 2048 + si] = val;
        }
      }
    }
  }
}

// ---------------------------------------------------------------- GEMM2: out = z @ Wo^T (f32 out)
__global__ __launch_bounds__(256) void gemm_out_k(
    const uint16_t* __restrict__ A,   // [4096][2048] bf16 (z in [b,s,d])
    const uint16_t* __restrict__ B,   // [2048][2048] bf16 (Wo)
    float* __restrict__ C) {          // [4096][2048] f32
  __shared__ uint16_t Ash[128 * 32];
  __shared__ uint16_t Bsh[128 * 32];
  const int t = threadIdx.x;
  const int lane = t & 63;
  const int w = t >> 6, wr = w >> 1, wc = w & 1;
  const int fr = lane & 15, fg = lane >> 4, fk = fg * 8;
  const int m0 = blockIdx.x * 128, n0 = blockIdx.y * 128;
  const int K = 2048;

  f32x4 acc[4][4];
#pragma unroll
  for (int i = 0; i < 4; i++)
#pragma unroll
    for (int j = 0; j < 4; j++) acc[i][j] = (f32x4)(0.0f);

  for (int kt = 0; kt < K; kt += 32) {
    __syncthreads();
    {
      int c0 = t, c1 = t + 256;
      gll16(&A[(size_t)(m0 + (c0 >> 2)) * K + kt + (c0 & 3) * 8], &Ash[(c0 & ~63) * 8]);
      gll16(&A[(size_t)(m0 + (c1 >> 2)) * K + kt + (c1 & 3) * 8], &Ash[(c1 & ~63) * 8]);
      gll16(&B[(size_t)(n0 + (c0 >> 2)) * K + kt + (c0 & 3) * 8], &Bsh[(c0 & ~63) * 8]);
      gll16(&B[(size_t)(n0 + (c1 >> 2)) * K + kt + (c1 & 3) * 8], &Bsh[(c1 & ~63) * 8]);
    }
    __syncthreads();
    bf16x8 af[4], bfr[4];
#pragma unroll
    for (int mi = 0; mi < 4; mi++) af[mi] = *(const bf16x8*)&Ash[(wr * 64 + mi * 16 + fr) * 32 + fk];
#pragma unroll
    for (int ni = 0; ni < 4; ni++) bfr[ni] = *(const bf16x8*)&Bsh[(wc * 64 + ni * 16 + fr) * 32 + fk];
#pragma unroll
    for (int mi = 0; mi < 4; mi++)
#pragma unroll
      for (int ni = 0; ni < 4; ni++)
        acc[mi][ni] = __builtin_amdgcn_mfma_f32_16x16x32_bf16(af[mi], bfr[ni], acc[mi][ni], 0, 0, 0);
  }

#pragma unroll
  for (int mi = 0; mi < 4; mi++) {
#pragma unroll
    for (int ni = 0; ni < 4; ni++) {
      int ng = n0 + wc * 64 + ni * 16 + fr;
#pragma unroll
      for (int r = 0; r < 4; r++) {
        int mg = m0 + wr * 64 + mi * 16 + fg * 4 + r;
        C[(size_t)mg * 2048 + ng] = acc[mi][ni][r];
      }
    }
  }
}

// ---------------------------------------------------------------- flash attention (causal)
// Q,K: [b,h,2048,128] bf16; Vt: [b,h,128,2048] bf16 (pre-transposed)
// block: 256 thr (4 waves), each wave 32 q-rows -> 128 q-rows/block, kv tiles of 64
// grid (16, 32); bx remapped so paired blocks have complementary causal work
__global__ __launch_bounds__(256, 2) void attn_kernel(
    const uint16_t* __restrict__ Qb, const uint16_t* __restrict__ Kb,
    const uint16_t* __restrict__ Vt, uint16_t* __restrict__ zb) {
  __shared__ uint16_t Ksh[64 * 128];    // [kv 64][d 128], 16B-chunk xor-swizzled by (row&7)
  __shared__ uint16_t Vsh[128 * 64];    // [d 128][kv 64], 16B-chunk xor-swizzled by (d&7)
  __shared__ uint16_t Psh[4][32][72];   // per-wave P[32 q][64 kv], +8 pad

  const int t = threadIdx.x, lane = t & 63, w = t >> 6;
  const int fr = lane & 15, fg = lane >> 4, fk = fg * 8;
  const int bx = blockIdx.x, bh = blockIdx.y;
  const int qt = (bx < 8) ? bx : 23 - bx;     // pair (i, 15-i): uniform 34 kv-tiles/pair
  const int q0 = qt * 128;
  const size_t hbase = (size_t)bh * 2048 * 128;
  const float scale2 = 0.08838834764831845f * 1.4426950408889634f;  // * log2(e)

  // Q fragments: rows q0 + w*32 + qs*16 + fr
  bf16x8 qf[2][4];
#pragma unroll
  for (int qs = 0; qs < 2; ++qs)
#pragma unroll
    for (int dc = 0; dc < 4; ++dc)
      qf[qs][dc] = *(const bf16x8*)&Qb[hbase + (size_t)(q0 + w * 32 + qs * 16 + fr) * 128 + dc * 32 + fk];

  f32x4 oacc[2][8];
#pragma unroll
  for (int qs = 0; qs < 2; ++qs)
#pragma unroll
    for (int i = 0; i < 8; i++) oacc[qs][i] = (f32x4)(0.0f);
  float mrow[2][4], lrow[2][4];
#pragma unroll
  for (int qs = 0; qs < 2; ++qs)
#pragma unroll
    for (int r = 0; r < 4; r++) { mrow[qs][r] = -1e30f; lrow[qs][r] = 0.0f; }

  const int ktiles = 2 * qt + 2;
  for (int kt = 0; kt < ktiles; ++kt) {
    __syncthreads();
    const uint16_t* Kg = Kb + hbase + (size_t)kt * 64 * 128;
    const uint16_t* Vg = Vt + hbase + (size_t)kt * 64;
#pragma unroll
    for (int i = 0; i < 4; i++) {
      int c = t + i * 256;
      { int row = c >> 4, cc = c & 15, scc = cc ^ (row & 7);
        gll16(&Kg[row * 128 + scc * 8], &Ksh[(c & ~63) * 8]); }
      { int r = c >> 3, cc = c & 7, scc = cc ^ (r & 7);
        gll16(&Vg[(size_t)r * 2048 + scc * 8], &Vsh[(c & ~63) * 8]); }
    }
    __syncthreads();

    const int kv_base = kt * 64;
    if (kv_base <= q0 + w * 32 + 31) {   // wave has at least one unmasked row
      // ---- QK^T: S[32q][64kv] per wave (two 16-row sub-tiles share K frags)
      f32x4 sacc[2][4];
#pragma unroll
      for (int qs = 0; qs < 2; ++qs)
#pragma unroll
        for (int kv16 = 0; kv16 < 4; ++kv16) sacc[qs][kv16] = (f32x4)(0.0f);
      __builtin_amdgcn_s_setprio(1);
#pragma unroll
      for (int kv16 = 0; kv16 < 4; ++kv16) {
        int row = kv16 * 16 + fr;
#pragma unroll
        for (int dc = 0; dc < 4; ++dc) {
          int sc = (dc * 4 + fg) ^ (row & 7);
          bf16x8 kf = *(const bf16x8*)&Ksh[row * 128 + sc * 8];
          sacc[0][kv16] = __builtin_amdgcn_mfma_f32_16x16x32_bf16(qf[0][dc], kf, sacc[0][kv16], 0, 0, 0);
          sacc[1][kv16] = __builtin_amdgcn_mfma_f32_16x16x32_bf16(qf[1][dc], kf, sacc[1][kv16], 0, 0, 0);
        }
      }
      __builtin_amdgcn_s_setprio(0);

      // ---- scale + mask + online softmax (in log2 space)
      const bool need_mask = (kv_base + 63 > q0 + w * 32);
      float alpha[2][4];
#pragma unroll
      for (int qs = 0; qs < 2; ++qs) {
#pragma unroll
        for (int r = 0; r < 4; ++r) {
          int rowg = q0 + w * 32 + qs * 16 + fg * 4 + r;
          float s0 = sacc[qs][0][r] * scale2, s1 = sacc[qs][1][r] * scale2;
          float s2 = sacc[qs][2][r] * scale2, s3 = sacc[qs][3][r] * scale2;
          if (need_mask) {
            if (kv_base + 0 * 16 + fr > rowg) s0 = -1e30f;
            if (kv_base + 1 * 16 + fr > rowg) s1 = -1e30f;
            if (kv_base + 2 * 16 + fr > rowg) s2 = -1e30f;
            if (kv_base + 3 * 16 + fr > rowg) s3 = -1e30f;
          }
          float mx = fmaxf(fmaxf(s0, s1), fmaxf(s2, s3));
#pragma unroll
          for (int off = 1; off < 16; off <<= 1) mx = fmaxf(mx, __shfl_xor(mx, off, 64));
          float mnew = fmaxf(mrow[qs][r], mx);
          alpha[qs][r] = exp2f(mrow[qs][r] - mnew);
          mrow[qs][r] = mnew;
          float p0 = exp2f(s0 - mnew), p1 = exp2f(s1 - mnew);
          float p2 = exp2f(s2 - mnew), p3 = exp2f(s3 - mnew);
          float ps = p0 + p1 + p2 + p3;
#pragma unroll
          for (int off = 1; off < 16; off <<= 1) ps += __shfl_xor(ps, off, 64);
          lrow[qs][r] = lrow[qs][r] * alpha[qs][r] + ps;
          int ql = qs * 16 + fg * 4 + r;
          Psh[w][ql][0 * 16 + fr] = f2bf(p0);
          Psh[w][ql][1 * 16 + fr] = f2bf(p1);
          Psh[w][ql][2 * 16 + fr] = f2bf(p2);
          Psh[w][ql][3 * 16 + fr] = f2bf(p3);
        }
#pragma unroll
        for (int i = 0; i < 8; i++)
#pragma unroll
          for (int r = 0; r < 4; r++) oacc[qs][i][r] *= alpha[qs][r];
      }

      asm volatile("s_waitcnt lgkmcnt(0)" ::: "memory");  // P writes visible to this wave

      // ---- PV: O[32q][128d] += P[32][64] * V[64][128]  (V frags shared by both qs)
      __builtin_amdgcn_s_setprio(1);
#pragma unroll
      for (int kc = 0; kc < 2; ++kc) {
        bf16x8 pf0 = *(const bf16x8*)&Psh[w][fr][kc * 32 + fk];
        bf16x8 pf1 = *(const bf16x8*)&Psh[w][16 + fr][kc * 32 + fk];
#pragma unroll
        for (int n8 = 0; n8 < 8; ++n8) {
          int d = n8 * 16 + fr;
          bf16x8 vf = *(const bf16x8*)((const char*)Vsh +
                        d * 128 + (((kc * 4 + fg) ^ (d & 7)) * 16));
          oacc[0][n8] = __builtin_amdgcn_mfma_f32_16x16x32_bf16(pf0, vf, oacc[0][n8], 0, 0, 0);
          oacc[1][n8] = __builtin_amdgcn_mfma_f32_16x16x32_bf16(pf1, vf, oacc[1][n8], 0, 0, 0);
        }
      }
      __builtin_amdgcn_s_setprio(0);
    }
  }

  // ---- normalize + write z in [b, s, h*128+d]
  const int b = bh >> 4, h = bh & 15;
#pragma unroll
  for (int qs = 0; qs < 2; ++qs)
#pragma unroll
    for (int n8 = 0; n8 < 8; ++n8)
#pragma unroll
      for (int r = 0; r < 4; ++r) {
        int rowg = q0 + w * 32 + qs * 16 + fg * 4 + r;
        int d = n8 * 16 + fr;
        float o = oacc[qs][n8][r] / lrow[qs][r];
        zb[((size_t)b * 2048 + rowg) * 2048 + h * 128 + d] = f2bf(o);
      }
}

// ---------------------------------------------------------------- launch
extern "C" void kernel_launch(void* const* d_in, const int* in_sizes, int n_in,
                              void* d_out, int out_size, void* d_ws, size_t ws_size,
                              hipStream_t stream) {
  const float* x    = (const float*)d_in[0];
  const float* Wqkv = (const float*)d_in[1];
  const float* Wo   = (const float*)d_in[2];
  float* out = (float*)d_out;
  char* ws = (char*)d_ws;

  uint16_t* Qb    = (uint16_t*)(ws + 0);            // 16 MB
  uint16_t* Kb    = (uint16_t*)(ws + 16777216);     // 16 MB
  uint16_t* Vt    = (uint16_t*)(ws + 33554432);     // 16 MB  [b,h,128,2048]
  uint16_t* xb    = (uint16_t*)(ws + 50331648);     // 16 MB (dead after gemm_qkv)
  uint16_t* zb    = (uint16_t*)(ws + 50331648);     // alias xb
  uint16_t* wqkvb = (uint16_t*)(ws + 67108864);     // 24 MB
  uint16_t* wob   = (uint16_t*)(ws + 92274688);     //  8 MB
  float*    cosT  = (float*)   (ws + 100663296);
  float*    sinT  = (float*)   (ws + 101187584);

  cvt_f32_bf16<<<4096, 256, 0, stream>>>(x, xb, 8388608 / 8);
  cvt_f32_bf16<<<6144, 256, 0, stream>>>(Wqkv, wqkvb, 12582912 / 8);
  cvt_f32_bf16<<<2048, 256, 0, stream>>>(Wo, wob, 4194304 / 8);
  rope_table<<<512, 256, 0, stream>>>(cosT, sinT);

  gemm_qkv<<<dim3(32, 48), 256, 0, stream>>>(xb, wqkvb, Qb, Kb, Vt);

  rope_apply<<<16384, 256, 0, stream>>>(Qb, cosT, sinT);
  rope_apply<<<16384, 256, 0, stream>>>(Kb, cosT, sinT);

  attn_kernel<<<dim3(16, 32), 256, 0, stream>>>(Qb, Kb, Vt, zb);

  gemm_out_k<<<dim3(32, 16), 256, 0, stream>>>(zb, wob, out);
}

// Round 3
// 367.163 us; speedup vs baseline: 1.1964x; 1.1351x over previous
//
#include <hip/hip_runtime.h>
#include <stdint.h>
#include <stddef.h>

typedef __attribute__((ext_vector_type(8))) short bf16x8;
typedef __attribute__((ext_vector_type(4))) float f32x4;
typedef __attribute__((ext_vector_type(4))) unsigned int u32x4;

#define AS1 __attribute__((address_space(1)))
#define AS3 __attribute__((address_space(3)))

__device__ __forceinline__ void gll16(const void* g, void* l) {
  __builtin_amdgcn_global_load_lds((const AS1 unsigned int*)g, (AS3 unsigned int*)l, 16, 0, 0);
}

__device__ __forceinline__ uint16_t f2bf(float f) {
  uint32_t u = __builtin_bit_cast(uint32_t, f);
  u += 0x7fffu + ((u >> 16) & 1u);
  return (uint16_t)(u >> 16);
}
__device__ __forceinline__ float bf2f(uint16_t h) {
  uint32_t u = ((uint32_t)h) << 16;
  return __builtin_bit_cast(float, u);
}

// ---------------------------------------------------------------- f32 -> bf16
__global__ void cvt_f32_bf16(const float* __restrict__ in, uint16_t* __restrict__ out, int n8) {
  int i = blockIdx.x * blockDim.x + threadIdx.x;
  if (i >= n8) return;
  float4 a = reinterpret_cast<const float4*>(in)[2 * i];
  float4 b = reinterpret_cast<const float4*>(in)[2 * i + 1];
  union { uint16_t h[8]; u32x4 v; } u;
  u.h[0] = f2bf(a.x); u.h[1] = f2bf(a.y); u.h[2] = f2bf(a.z); u.h[3] = f2bf(a.w);
  u.h[4] = f2bf(b.x); u.h[5] = f2bf(b.y); u.h[6] = f2bf(b.z); u.h[7] = f2bf(b.w);
  reinterpret_cast<u32x4*>(out)[i] = u.v;
}

// ---------------------------------------------------------------- RoPE table
__global__ void rope_table(float* __restrict__ cosT, float* __restrict__ sinT) {
  int idx = blockIdx.x * blockDim.x + threadIdx.x;  // 2048*64
  int s = idx >> 6, i = idx & 63;
  float invf = expf(-(float)i * (9.2103403719761836f / 64.0f));
  float f = (float)s * invf;
  cosT[idx] = cosf(f);
  sinT[idx] = sinf(f);
}

// ---------------------------------------------------------------- RoPE apply (in place on [2,16,2048,128] bf16)
__global__ void rope_apply(uint16_t* __restrict__ buf,
                           const float* __restrict__ cosT, const float* __restrict__ sinT) {
  int idx = blockIdx.x * blockDim.x + threadIdx.x;  // 2*16*2048*64 = 4194304
  int i = idx & 63;
  int s = (idx >> 6) & 2047;
  int bh = idx >> 17;
  size_t base = ((size_t)bh * 2048 + s) * 128;
  float x0 = bf2f(buf[base + i]);
  float x1 = bf2f(buf[base + i + 64]);
  float c = cosT[(s << 6) + i], sn = sinT[(s << 6) + i];
  buf[base + i]      = f2bf(x0 * c - x1 * sn);
  buf[base + i + 64] = f2bf(x1 * c + x0 * sn);
}

// ---------------------------------------------------------------- GEMM1: qkv = x @ Wqkv^T
// Q,K scatter to [b,h,s,dh]; V scatters TRANSPOSED to Vt[b,h,dh,s] (packed 8B stores)
__global__ __launch_bounds__(256) void gemm_qkv(
    const uint16_t* __restrict__ A,   // [4096][2048]
    const uint16_t* __restrict__ B,   // [6144][2048]
    uint16_t* __restrict__ Qb, uint16_t* __restrict__ Kb, uint16_t* __restrict__ Vt) {
  __shared__ uint16_t Ash[128 * 32];
  __shared__ uint16_t Bsh[128 * 32];
  const int t = threadIdx.x;
  const int lane = t & 63;
  const int w = t >> 6, wr = w >> 1, wc = w & 1;
  const int fr = lane & 15, fg = lane >> 4, fk = fg * 8;
  const int m0 = blockIdx.x * 128, n0 = blockIdx.y * 128;
  const int K = 2048;

  f32x4 acc[4][4];
#pragma unroll
  for (int i = 0; i < 4; i++)
#pragma unroll
    for (int j = 0; j < 4; j++) acc[i][j] = (f32x4)(0.0f);

  for (int kt = 0; kt < K; kt += 32) {
    __syncthreads();
    {
      int c0 = t, c1 = t + 256;
      gll16(&A[(size_t)(m0 + (c0 >> 2)) * K + kt + (c0 & 3) * 8], &Ash[(c0 & ~63) * 8]);
      gll16(&A[(size_t)(m0 + (c1 >> 2)) * K + kt + (c1 & 3) * 8], &Ash[(c1 & ~63) * 8]);
      gll16(&B[(size_t)(n0 + (c0 >> 2)) * K + kt + (c0 & 3) * 8], &Bsh[(c0 & ~63) * 8]);
      gll16(&B[(size_t)(n0 + (c1 >> 2)) * K + kt + (c1 & 3) * 8], &Bsh[(c1 & ~63) * 8]);
    }
    __syncthreads();
    bf16x8 af[4], bfr[4];
#pragma unroll
    for (int mi = 0; mi < 4; mi++) af[mi] = *(const bf16x8*)&Ash[(wr * 64 + mi * 16 + fr) * 32 + fk];
#pragma unroll
    for (int ni = 0; ni < 4; ni++) bfr[ni] = *(const bf16x8*)&Bsh[(wc * 64 + ni * 16 + fr) * 32 + fk];
#pragma unroll
    for (int mi = 0; mi < 4; mi++)
#pragma unroll
      for (int ni = 0; ni < 4; ni++)
        acc[mi][ni] = __builtin_amdgcn_mfma_f32_16x16x32_bf16(af[mi], bfr[ni], acc[mi][ni], 0, 0, 0);
  }

#pragma unroll
  for (int mi = 0; mi < 4; mi++) {
#pragma unroll
    for (int ni = 0; ni < 4; ni++) {
      int ng = n0 + wc * 64 + ni * 16 + fr;
      int head = (ng >> 7) & 15, dd = ng & 127;
      if (ng < 4096) {
        uint16_t* dst = (ng < 2048) ? Qb : Kb;
#pragma unroll
        for (int r = 0; r < 4; r++) {
          int mg = m0 + wr * 64 + mi * 16 + fg * 4 + r;
          int b = mg >> 11, si = mg & 2047;
          dst[((size_t)(b * 16 + head) * 2048 + si) * 128 + dd] = f2bf(acc[mi][ni][r]);
        }
      } else {
        // packed 8B store: 4 consecutive si for this lane's (dd) row of Vt
        uint32_t h0 = f2bf(acc[mi][ni][0]), h1 = f2bf(acc[mi][ni][1]);
        uint32_t h2 = f2bf(acc[mi][ni][2]), h3 = f2bf(acc[mi][ni][3]);
        uint2 pv = make_uint2(h0 | (h1 << 16), h2 | (h3 << 16));
        int mg = m0 + wr * 64 + mi * 16 + fg * 4;
        int b = mg >> 11, si = mg & 2047;
        *(uint2*)&Vt[((size_t)(b * 16 + head) * 128 + dd) * 2048 + si] = pv;
      }
    }
  }
}

// ---------------------------------------------------------------- GEMM2: out = z @ Wo^T (f32 out)
__global__ __launch_bounds__(256) void gemm_out_k(
    const uint16_t* __restrict__ A,   // [4096][2048] bf16 (z in [b,s,d])
    const uint16_t* __restrict__ B,   // [2048][2048] bf16 (Wo)
    float* __restrict__ C) {          // [4096][2048] f32
  __shared__ uint16_t Ash[128 * 32];
  __shared__ uint16_t Bsh[128 * 32];
  const int t = threadIdx.x;
  const int lane = t & 63;
  const int w = t >> 6, wr = w >> 1, wc = w & 1;
  const int fr = lane & 15, fg = lane >> 4, fk = fg * 8;
  const int m0 = blockIdx.x * 128, n0 = blockIdx.y * 128;
  const int K = 2048;

  f32x4 acc[4][4];
#pragma unroll
  for (int i = 0; i < 4; i++)
#pragma unroll
    for (int j = 0; j < 4; j++) acc[i][j] = (f32x4)(0.0f);

  for (int kt = 0; kt < K; kt += 32) {
    __syncthreads();
    {
      int c0 = t, c1 = t + 256;
      gll16(&A[(size_t)(m0 + (c0 >> 2)) * K + kt + (c0 & 3) * 8], &Ash[(c0 & ~63) * 8]);
      gll16(&A[(size_t)(m0 + (c1 >> 2)) * K + kt + (c1 & 3) * 8], &Ash[(c1 & ~63) * 8]);
      gll16(&B[(size_t)(n0 + (c0 >> 2)) * K + kt + (c0 & 3) * 8], &Bsh[(c0 & ~63) * 8]);
      gll16(&B[(size_t)(n0 + (c1 >> 2)) * K + kt + (c1 & 3) * 8], &Bsh[(c1 & ~63) * 8]);
    }
    __syncthreads();
    bf16x8 af[4], bfr[4];
#pragma unroll
    for (int mi = 0; mi < 4; mi++) af[mi] = *(const bf16x8*)&Ash[(wr * 64 + mi * 16 + fr) * 32 + fk];
#pragma unroll
    for (int ni = 0; ni < 4; ni++) bfr[ni] = *(const bf16x8*)&Bsh[(wc * 64 + ni * 16 + fr) * 32 + fk];
#pragma unroll
    for (int mi = 0; mi < 4; mi++)
#pragma unroll
      for (int ni = 0; ni < 4; ni++)
        acc[mi][ni] = __builtin_amdgcn_mfma_f32_16x16x32_bf16(af[mi], bfr[ni], acc[mi][ni], 0, 0, 0);
  }

#pragma unroll
  for (int mi = 0; mi < 4; mi++) {
#pragma unroll
    for (int ni = 0; ni < 4; ni++) {
      int ng = n0 + wc * 64 + ni * 16 + fr;
#pragma unroll
      for (int r = 0; r < 4; r++) {
        int mg = m0 + wr * 64 + mi * 16 + fg * 4 + r;
        C[(size_t)mg * 2048 + ng] = acc[mi][ni][r];
      }
    }
  }
}

// ---------------------------------------------------------------- flash attention (causal)
// Q,K: [b,h,2048,128] bf16; Vt: [b,h,128,2048] bf16 (pre-transposed)
// block: 256 thr (4 waves), each wave 32 q-rows -> 128 q-rows/block, kv tiles of 64
// grid (16, 32); qt chosen so CU-paired blocks (i, i+256: same bx, bh^16) have
// complementary causal depth -> every CU gets exactly 34 kv-tiles of work
__global__ __launch_bounds__(256, 2) void attn_kernel(
    const uint16_t* __restrict__ Qb, const uint16_t* __restrict__ Kb,
    const uint16_t* __restrict__ Vt, uint16_t* __restrict__ zb) {
  __shared__ uint16_t Ksh[64 * 128];    // [kv 64][d 128], 16B-chunk xor-swizzled by (row&7)
  __shared__ uint16_t Vsh[128 * 64];    // [d 128][kv 64], 16B-chunk xor-swizzled by (d&7)
  __shared__ uint16_t Psh[4][32][72];   // per-wave P[32 q][64 kv], +8 pad

  const int t = threadIdx.x, lane = t & 63, w = t >> 6;
  const int fr = lane & 15, fg = lane >> 4, fk = fg * 8;
  const int bx = blockIdx.x, bh = blockIdx.y;
  const int qt = (bh & 16) ? (15 - bx) : bx;   // CU-pair balance: qt + qt' = 15
  const int q0 = qt * 128;
  const size_t hbase = (size_t)bh * 2048 * 128;
  const float scale2 = 0.08838834764831845f * 1.4426950408889634f;  // * log2(e)

  // Q fragments: rows q0 + w*32 + qs*16 + fr
  bf16x8 qf[2][4];
#pragma unroll
  for (int qs = 0; qs < 2; ++qs)
#pragma unroll
    for (int dc = 0; dc < 4; ++dc)
      qf[qs][dc] = *(const bf16x8*)&Qb[hbase + (size_t)(q0 + w * 32 + qs * 16 + fr) * 128 + dc * 32 + fk];

  f32x4 oacc[2][8];
#pragma unroll
  for (int qs = 0; qs < 2; ++qs)
#pragma unroll
    for (int i = 0; i < 8; i++) oacc[qs][i] = (f32x4)(0.0f);
  float mrow[2][4], lrow[2][4];
#pragma unroll
  for (int qs = 0; qs < 2; ++qs)
#pragma unroll
    for (int r = 0; r < 4; r++) { mrow[qs][r] = -1e30f; lrow[qs][r] = 0.0f; }

  const int ktiles = 2 * qt + 2;
  for (int kt = 0; kt < ktiles; ++kt) {
    __syncthreads();
    const uint16_t* Kg = Kb + hbase + (size_t)kt * 64 * 128;
    const uint16_t* Vg = Vt + hbase + (size_t)kt * 64;
#pragma unroll
    for (int i = 0; i < 4; i++) {
      int c = t + i * 256;
      { int row = c >> 4, cc = c & 15, scc = cc ^ (row & 7);
        gll16(&Kg[row * 128 + scc * 8], &Ksh[(c & ~63) * 8]); }
      { int r = c >> 3, cc = c & 7, scc = cc ^ (r & 7);
        gll16(&Vg[(size_t)r * 2048 + scc * 8], &Vsh[(c & ~63) * 8]); }
    }
    __syncthreads();

    const int kv_base = kt * 64;
    if (kv_base <= q0 + w * 32 + 31) {   // wave has at least one unmasked row
      // ---- QK^T: S[32q][64kv] per wave (two 16-row sub-tiles share K frags)
      f32x4 sacc[2][4];
#pragma unroll
      for (int qs = 0; qs < 2; ++qs)
#pragma unroll
        for (int kv16 = 0; kv16 < 4; ++kv16) sacc[qs][kv16] = (f32x4)(0.0f);
      __builtin_amdgcn_s_setprio(1);
#pragma unroll
      for (int kv16 = 0; kv16 < 4; ++kv16) {
        int row = kv16 * 16 + fr;
#pragma unroll
        for (int dc = 0; dc < 4; ++dc) {
          int sc = (dc * 4 + fg) ^ (row & 7);
          bf16x8 kf = *(const bf16x8*)&Ksh[row * 128 + sc * 8];
          sacc[0][kv16] = __builtin_amdgcn_mfma_f32_16x16x32_bf16(qf[0][dc], kf, sacc[0][kv16], 0, 0, 0);
          sacc[1][kv16] = __builtin_amdgcn_mfma_f32_16x16x32_bf16(qf[1][dc], kf, sacc[1][kv16], 0, 0, 0);
        }
      }
      __builtin_amdgcn_s_setprio(0);

      // ---- scale + mask + online softmax (in log2 space)
      const bool need_mask = (kv_base + 63 > q0 + w * 32);
      float alpha[2][4];
#pragma unroll
      for (int qs = 0; qs < 2; ++qs) {
#pragma unroll
        for (int r = 0; r < 4; ++r) {
          int rowg = q0 + w * 32 + qs * 16 + fg * 4 + r;
          float s0 = sacc[qs][0][r] * scale2, s1 = sacc[qs][1][r] * scale2;
          float s2 = sacc[qs][2][r] * scale2, s3 = sacc[qs][3][r] * scale2;
          if (need_mask) {
            if (kv_base + 0 * 16 + fr > rowg) s0 = -1e30f;
            if (kv_base + 1 * 16 + fr > rowg) s1 = -1e30f;
            if (kv_base + 2 * 16 + fr > rowg) s2 = -1e30f;
            if (kv_base + 3 * 16 + fr > rowg) s3 = -1e30f;
          }
          float mx = fmaxf(fmaxf(s0, s1), fmaxf(s2, s3));
#pragma unroll
          for (int off = 1; off < 16; off <<= 1) mx = fmaxf(mx, __shfl_xor(mx, off, 64));
          float mnew = fmaxf(mrow[qs][r], mx);
          alpha[qs][r] = exp2f(mrow[qs][r] - mnew);
          mrow[qs][r] = mnew;
          float p0 = exp2f(s0 - mnew), p1 = exp2f(s1 - mnew);
          float p2 = exp2f(s2 - mnew), p3 = exp2f(s3 - mnew);
          float ps = p0 + p1 + p2 + p3;
#pragma unroll
          for (int off = 1; off < 16; off <<= 1) ps += __shfl_xor(ps, off, 64);
          lrow[qs][r] = lrow[qs][r] * alpha[qs][r] + ps;
          int ql = qs * 16 + fg * 4 + r;
          Psh[w][ql][0 * 16 + fr] = f2bf(p0);
          Psh[w][ql][1 * 16 + fr] = f2bf(p1);
          Psh[w][ql][2 * 16 + fr] = f2bf(p2);
          Psh[w][ql][3 * 16 + fr] = f2bf(p3);
        }
#pragma unroll
        for (int i = 0; i < 8; i++)
#pragma unroll
          for (int r = 0; r < 4; r++) oacc[qs][i][r] *= alpha[qs][r];
      }

      asm volatile("s_waitcnt lgkmcnt(0)" ::: "memory");  // P writes visible to this wave

      // ---- PV: O[32q][128d] += P[32][64] * V[64][128]  (V frags shared by both qs)
      __builtin_amdgcn_s_setprio(1);
#pragma unroll
      for (int kc = 0; kc < 2; ++kc) {
        bf16x8 pf0 = *(const bf16x8*)&Psh[w][fr][kc * 32 + fk];
        bf16x8 pf1 = *(const bf16x8*)&Psh[w][16 + fr][kc * 32 + fk];
#pragma unroll
        for (int n8 = 0; n8 < 8; ++n8) {
          int d = n8 * 16 + fr;
          bf16x8 vf = *(const bf16x8*)((const char*)Vsh +
                        d * 128 + (((kc * 4 + fg) ^ (d & 7)) * 16));
          oacc[0][n8] = __builtin_amdgcn_mfma_f32_16x16x32_bf16(pf0, vf, oacc[0][n8], 0, 0, 0);
          oacc[1][n8] = __builtin_amdgcn_mfma_f32_16x16x32_bf16(pf1, vf, oacc[1][n8], 0, 0, 0);
        }
      }
      __builtin_amdgcn_s_setprio(0);
    }
  }

  // ---- normalize + write z in [b, s, h*128+d]
  const int b = bh >> 4, h = bh & 15;
#pragma unroll
  for (int qs = 0; qs < 2; ++qs)
#pragma unroll
    for (int n8 = 0; n8 < 8; ++n8)
#pragma unroll
      for (int r = 0; r < 4; ++r) {
        int rowg = q0 + w * 32 + qs * 16 + fg * 4 + r;
        int d = n8 * 16 + fr;
        float o = oacc[qs][n8][r] / lrow[qs][r];
        zb[((size_t)b * 2048 + rowg) * 2048 + h * 128 + d] = f2bf(o);
      }
}

// ---------------------------------------------------------------- launch
extern "C" void kernel_launch(void* const* d_in, const int* in_sizes, int n_in,
                              void* d_out, int out_size, void* d_ws, size_t ws_size,
                              hipStream_t stream) {
  const float* x    = (const float*)d_in[0];
  const float* Wqkv = (const float*)d_in[1];
  const float* Wo   = (const float*)d_in[2];
  float* out = (float*)d_out;
  char* ws = (char*)d_ws;

  uint16_t* Qb    = (uint16_t*)(ws + 0);            // 16 MB
  uint16_t* Kb    = (uint16_t*)(ws + 16777216);     // 16 MB
  uint16_t* Vt    = (uint16_t*)(ws + 33554432);     // 16 MB  [b,h,128,2048]
  uint16_t* xb    = (uint16_t*)(ws + 50331648);     // 16 MB (dead after gemm_qkv)
  uint16_t* zb    = (uint16_t*)(ws + 50331648);     // alias xb
  uint16_t* wqkvb = (uint16_t*)(ws + 67108864);     // 24 MB
  uint16_t* wob   = (uint16_t*)(ws + 92274688);     //  8 MB
  float*    cosT  = (float*)   (ws + 100663296);
  float*    sinT  = (float*)   (ws + 101187584);

  cvt_f32_bf16<<<4096, 256, 0, stream>>>(x, xb, 8388608 / 8);
  cvt_f32_bf16<<<6144, 256, 0, stream>>>(Wqkv, wqkvb, 12582912 / 8);
  cvt_f32_bf16<<<2048, 256, 0, stream>>>(Wo, wob, 4194304 / 8);
  rope_table<<<512, 256, 0, stream>>>(cosT, sinT);

  gemm_qkv<<<dim3(32, 48), 256, 0, stream>>>(xb, wqkvb, Qb, Kb, Vt);

  rope_apply<<<16384, 256, 0, stream>>>(Qb, cosT, sinT);
  rope_apply<<<16384, 256, 0, stream>>>(Kb, cosT, sinT);

  attn_kernel<<<dim3(16, 32), 256, 0, stream>>>(Qb, Kb, Vt, zb);

  gemm_out_k<<<dim3(32, 16), 256, 0, stream>>>(zb, wob, out);
}